// Round 6
// baseline (190.985 us; speedup 1.0000x reference)
//
#include <hip/hip_runtime.h>
#include <stdint.h>

#define SEQ   4096
#define EMB   1024
#define HD    128
#define WIN   256
#define MROWS 8192   // SEQ*B

typedef unsigned short u16;
typedef unsigned long long u64;
typedef __bf16 v8bf  __attribute__((ext_vector_type(8)));
typedef float  v4f   __attribute__((ext_vector_type(4)));
typedef u16    v8u16 __attribute__((ext_vector_type(8)));

__device__ __forceinline__ u16 f2bf(float f) {
  uint32_t u = __builtin_bit_cast(uint32_t, f);
  u += 0x7FFFu + ((u >> 16) & 1u);
  return (u16)(u >> 16);
}
__device__ __forceinline__ void gl_lds16(const u16* g, u16* l) {
  __builtin_amdgcn_global_load_lds((const __attribute__((address_space(1))) void*)g,
                                   (__attribute__((address_space(3))) void*)l,
                                   16, 0, 0);
}

// ---------------------------------------------------------------------------
// f32 -> bf16 conversion: val (8.4M) and Wq/Wk/Wv (1M each) into workspace.
// ---------------------------------------------------------------------------
__global__ __launch_bounds__(256)
void cvt_f32_bf16(const float* __restrict__ val,
                  const float* __restrict__ Wq,
                  const float* __restrict__ Wk,
                  const float* __restrict__ Wv,
                  u16* __restrict__ valbf, u16* __restrict__ Wbf)
{
  const int seg = blockIdx.y;
  const float* src; u16* dst; int nblk;
  if (seg == 0)      { src = val; dst = valbf;              nblk = 4096; }
  else if (seg == 1) { src = Wq;  dst = Wbf;                nblk = 512;  }
  else if (seg == 2) { src = Wk;  dst = Wbf + (1u << 20);   nblk = 512;  }
  else               { src = Wv;  dst = Wbf + (2u << 20);   nblk = 512;  }
  if ((int)blockIdx.x >= nblk) return;
  const int t = blockIdx.x * 256 + threadIdx.x;   // 8 elems per thread
  float4 a = ((const float4*)src)[2 * t];
  float4 b = ((const float4*)src)[2 * t + 1];
  v8u16 o;
  o[0] = f2bf(a.x); o[1] = f2bf(a.y); o[2] = f2bf(a.z); o[3] = f2bf(a.w);
  o[4] = f2bf(b.x); o[5] = f2bf(b.y); o[6] = f2bf(b.z); o[7] = f2bf(b.w);
  ((v8u16*)dst)[t] = o;
}

// ---------------------------------------------------------------------------
// Fused QKV GEMM. Q/K row-major (attention order); V stored TRANSPOSED as
// VT[(b*8+h)*128 + d][s]. Grid: bm fastest (x) so same A-slab => same XCD.
// (At the m97-structure plateau: 39% MfmaUtil, ~920 TF, 0 bank conflicts.)
// ---------------------------------------------------------------------------
__global__ __launch_bounds__(256, 3)
void qkv_gemm(const u16* __restrict__ valbf, const u16* __restrict__ Wbf,
              const float* __restrict__ bq, const float* __restrict__ bk,
              const float* __restrict__ bv,
              u16* __restrict__ Qb, u16* __restrict__ Kb, u16* __restrict__ VTg)
{
  __shared__ __align__(16) u16 As[128 * 64];
  __shared__ __align__(16) u16 Bs[128 * 64];

  const int tid  = threadIdx.x;
  const int lane = tid & 63;
  const int w    = tid >> 6;
  const int quad = lane >> 4;
  const int lq   = lane & 15;
  const int wm   = w >> 1, wn = w & 1;

  const int bm = blockIdx.x;   // 0..63  (fastest -> XCD-local A slab)
  const int bn = blockIdx.y;   // 0..23

  const int seg = bn >> 3;     // 0=Q 1=K 2=V
  const u16*   Wsel = Wbf + (size_t)seg * EMB * EMB;
  const float* bsel = seg == 0 ? bq : (seg == 1 ? bk : bv);
  const int nseg0 = (bn & 7) * 128;

  const u16* arow[4];
  const u16* brow[4];
#pragma unroll
  for (int call = 0; call < 4; ++call) {
    int c  = call * 256 + w * 64 + lane;
    int m  = c >> 3;
    int qs = c & 7;
    int q  = qs ^ (m & 7);
    int a2 = bm * 128 + m;
    int aa = 2 * (a2 & 4095) + (a2 >> 12);
    int grow = (aa & 4095) * 2 + (aa >> 12);
    arow[call] = valbf + (size_t)grow * EMB + q * 8;
    int n = nseg0 + m;
    brow[call] = Wsel + (size_t)n * EMB + q * 8;
  }

  v4f acc[4][4];
#pragma unroll
  for (int mt = 0; mt < 4; ++mt)
#pragma unroll
    for (int nt = 0; nt < 4; ++nt) acc[mt][nt] = (v4f){0.f, 0.f, 0.f, 0.f};

#pragma unroll 1
  for (int kt = 0; kt < 16; ++kt) {
    const int k0 = kt * 64;
    __syncthreads();
#pragma unroll
    for (int call = 0; call < 4; ++call) {
      gl_lds16(arow[call] + k0, &As[(call * 256 + w * 64) * 8]);
      gl_lds16(brow[call] + k0, &Bs[(call * 256 + w * 64) * 8]);
    }
    __syncthreads();
#pragma unroll
    for (int ks = 0; ks < 2; ++ks) {
      v8bf afr[4], bfr[4];
      const int qa = ks * 4 + quad;
#pragma unroll
      for (int mt = 0; mt < 4; ++mt) {
        int m = wm * 64 + mt * 16 + lq;
        afr[mt] = *(const v8bf*)&As[(m * 8 + (qa ^ (m & 7))) * 8];
      }
#pragma unroll
      for (int nt = 0; nt < 4; ++nt) {
        int n = wn * 64 + nt * 16 + lq;
        bfr[nt] = *(const v8bf*)&Bs[(n * 8 + (qa ^ (n & 7))) * 8];
      }
#pragma unroll
      for (int mt = 0; mt < 4; ++mt)
#pragma unroll
        for (int nt = 0; nt < 4; ++nt)
          acc[mt][nt] = __builtin_amdgcn_mfma_f32_16x16x32_bf16(afr[mt], bfr[nt], acc[mt][nt], 0, 0, 0);
    }
  }

  const float scale = 0.08838834764831845f;  // 1/sqrt(128)
  float bias[4];
#pragma unroll
  for (int nt = 0; nt < 4; ++nt)
    bias[nt] = bsel[nseg0 + wn * 64 + nt * 16 + lq];

  if (seg == 2) {
    // V: store transposed, 4 m-consecutive values packed per 8B store
    const int h  = bn & 7;
    const int bp = bm >> 5;
    const int s0 = (bm & 31) * 128;
#pragma unroll
    for (int mt = 0; mt < 4; ++mt) {
      int mb = wm * 64 + mt * 16 + quad * 4;
#pragma unroll
      for (int nt = 0; nt < 4; ++nt) {
        int n = wn * 64 + nt * 16 + lq;   // = d (0..127)
        u64 pk = 0;
#pragma unroll
        for (int r = 0; r < 4; ++r)
          pk |= (u64)f2bf(acc[mt][nt][r] + bias[nt]) << (16 * r);
        *(u64*)&VTg[((size_t)(bp * 8 + h) * HD + n) * SEQ + s0 + mb] = pk;
      }
    }
  } else {
    u16* Osel = (seg == 0) ? Qb : Kb;
#pragma unroll
    for (int mt = 0; mt < 4; ++mt) {
      int rbase = bm * 128 + wm * 64 + mt * 16 + quad * 4;
#pragma unroll
      for (int nt = 0; nt < 4; ++nt) {
        int ncol = nseg0 + wn * 64 + nt * 16 + lq;
#pragma unroll
        for (int r = 0; r < 4; ++r) {
          float v = acc[mt][nt][r] + bias[nt];
          if (seg == 0) v *= scale;
          Osel[(size_t)(rbase + r) * EMB + ncol] = f2bf(v);
        }
      }
    }
  }
}

// ---------------------------------------------------------------------------
// Banded attention, 128-row Q tile (wave owns 32 rows = 2 m-tiles). K/V^T
// staged in LDS via coalesced global_load_lds, double-buffered, XOR-swizzled.
// V fragments hoisted to registers (read LDS once, used by both m-tiles);
// P roundtrip reuses one wave-private 16-row sP buffer per m-tile (DS ops are
// in-order per wave: no barrier). One barrier per key block. Zero-shift
// softmax; padding = exp(0)=1 in finalize; mask only on partial band tiles.
// LDS 73 KB -> 2 blocks/CU.
// ---------------------------------------------------------------------------
__global__ __launch_bounds__(256, 2)
void local_attn(const u16* __restrict__ Qb, const u16* __restrict__ Kb,
                const u16* __restrict__ VTg, float* __restrict__ out)
{
  __shared__ __align__(16) u16 sK [2][64 * 128];   // K tile  [j][d], swizzled
  __shared__ __align__(16) u16 sVT[2][128 * 64];   // V^T tile [d][j], swizzled
  __shared__ __align__(16) u16 sP [4][16 * 72];    // per-wave P tile (reused per mt)

  const int tid  = threadIdx.x;
  const int lane = tid & 63;
  const int w    = tid >> 6;
  const int quad = lane >> 4;
  const int lq   = lane & 15;

  const int bh = blockIdx.x;        // b'*8 + h  (fastest: same h -> same XCD)
  const int q0 = blockIdx.y * 128;
  const int bp = bh >> 3;
  const int h  = bh & 7;
  const size_t rowbase = (size_t)bp * SEQ;

  const u16* Kbase = Kb + rowbase * EMB + h * HD;       // + j*EMB
  const u16* Vbase = VTg + (size_t)bh * HD * SEQ;       // + d*SEQ

  // Q A-fragments for 2 m-tiles (pre-scaled in GEMM); one-time scattered load
  v8bf qf[2][4];
#pragma unroll
  for (int mt = 0; mt < 2; ++mt) {
    const u16* qrow = Qb + (rowbase + q0 + w * 32 + mt * 16 + lq) * EMB + h * HD;
#pragma unroll
    for (int ks = 0; ks < 4; ++ks)
      qf[mt][ks] = *(const v8bf*)(qrow + ks * 32 + quad * 8);
  }

  v4f oacc[2][8];
#pragma unroll
  for (int mt = 0; mt < 2; ++mt)
#pragma unroll
    for (int dt = 0; dt < 8; ++dt) oacc[mt][dt] = (v4f){0.f, 0.f, 0.f, 0.f};
  float ls[2][4] = {{0.f,0.f,0.f,0.f},{0.f,0.f,0.f,0.f}};

  const int jlo = (q0 - WIN > 0) ? q0 - WIN : 0;
  const int jhi = (q0 + 128 + WIN < SEQ) ? q0 + 128 + WIN : SEQ;
  const int nit = (jhi - jlo) >> 6;

  // coalesced DMA staging of one K tile (64x128) + one V^T tile (128x64)
  auto stage = [&](int kb, int p) {
#pragma unroll
    for (int call = 0; call < 4; ++call) {
      int s = call * 256 + w * 64 + lane;     // K slot (16B chunks)
      int row = s >> 4, sl = s & 15;
      int q = sl ^ (row & 15);
      gl_lds16(Kbase + (size_t)(kb + row) * EMB + q * 8,
               &sK[p][(call * 256 + w * 64) * 8]);
    }
#pragma unroll
    for (int call = 0; call < 4; ++call) {
      int s = call * 256 + w * 64 + lane;     // VT slot
      int d = s >> 3, sl = s & 7;
      int q = sl ^ (d & 7);
      gl_lds16(Vbase + (size_t)d * SEQ + kb + q * 8,
               &sVT[p][(call * 256 + w * 64) * 8]);
    }
  };

  stage(jlo, 0);   // prologue

#pragma unroll 1
  for (int it = 0; it < nit; ++it) {
    const int p  = it & 1;
    const int kb = jlo + it * 64;
    __syncthreads();                     // buf p DMA complete; buf p^1 free
    if (it + 1 < nit) stage(kb + 64, p ^ 1);

    // --- V^T fragments to registers (read once, used by both m-tiles) ---
    v8bf vf[2][8];
#pragma unroll
    for (int kv = 0; kv < 2; ++kv)
#pragma unroll
      for (int dt = 0; dt < 8; ++dt) {
        int d = dt * 16 + lq;
        vf[kv][dt] = *(const v8bf*)&sVT[p][(d * 8 + ((kv * 4 + quad) ^ (d & 7))) * 8];
      }

    // --- S = Q K^T from LDS (each kf feeds both m-tiles) ---
    v4f sfr[2][4];
#pragma unroll
    for (int mt = 0; mt < 2; ++mt)
#pragma unroll
      for (int nt = 0; nt < 4; ++nt) sfr[mt][nt] = (v4f){0.f, 0.f, 0.f, 0.f};
#pragma unroll
    for (int ks = 0; ks < 4; ++ks) {
      const int sl = (ks * 4 + quad) ^ lq;
#pragma unroll
      for (int nt = 0; nt < 4; ++nt) {
        v8bf kf = *(const v8bf*)&sK[p][((nt * 16 + lq) * 16 + sl) * 8];
        sfr[0][nt] = __builtin_amdgcn_mfma_f32_16x16x32_bf16(qf[0][ks], kf, sfr[0][nt], 0, 0, 0);
        sfr[1][nt] = __builtin_amdgcn_mfma_f32_16x16x32_bf16(qf[1][ks], kf, sfr[1][nt], 0, 0, 0);
      }
    }

    // --- per m-tile: exp + mask + denom + P roundtrip + PV ---
    const bool need_mask = (kb <= q0 - 192) || (kb >= q0 + 256);
#pragma unroll
    for (int mt = 0; mt < 2; ++mt) {
#pragma unroll
      for (int nt = 0; nt < 4; ++nt) {
#pragma unroll
        for (int r = 0; r < 4; ++r) {
          float pv = __expf(sfr[mt][nt][r]);
          if (need_mask) {
            int j  = kb + nt * 16 + lq;
            int sr = q0 + w * 32 + mt * 16 + quad * 4 + r;
            int dd = j - sr;
            pv = (dd <= WIN && dd >= -WIN) ? pv : 0.f;
          }
          ls[mt][r] += pv;
          sP[w][(quad * 4 + r) * 72 + nt * 16 + lq] = f2bf(pv);
        }
      }
      // O += P V (wave-private sP; DS in-order per wave => no barrier)
#pragma unroll
      for (int kv = 0; kv < 2; ++kv) {
        v8bf pf = *(const v8bf*)&sP[w][lq * 72 + kv * 32 + quad * 8];
#pragma unroll
        for (int dt = 0; dt < 8; ++dt)
          oacc[mt][dt] = __builtin_amdgcn_mfma_f32_16x16x32_bf16(pf, vf[kv][dt], oacc[mt][dt], 0, 0, 0);
      }
    }
  }

  // --- finalize: reduce denominators, add zero-padding count, store ---
#pragma unroll
  for (int mt = 0; mt < 2; ++mt) {
    float lrow[4];
#pragma unroll
    for (int r = 0; r < 4; ++r) {
      float t = ls[mt][r];
#pragma unroll
      for (int off = 1; off < 16; off <<= 1) t += __shfl_xor(t, off);
      int sr = q0 + w * 32 + mt * 16 + quad * 4 + r;
      int npl = WIN - sr;             if (npl < 0) npl = 0;
      int npr = sr - (SEQ - 1 - WIN); if (npr < 0) npr = 0;
      lrow[r] = t + (float)(npl + npr);
    }
#pragma unroll
    for (int dt = 0; dt < 8; ++dt) {
#pragma unroll
      for (int r = 0; r < 4; ++r) {
        int sr = q0 + w * 32 + mt * 16 + quad * 4 + r;
        out[(size_t)(2 * sr + bp) * EMB + h * HD + dt * 16 + lq] = oacc[mt][dt][r] / lrow[r];
      }
    }
  }
}

extern "C" void kernel_launch(void* const* d_in, const int* in_sizes, int n_in,
                              void* d_out, int out_size, void* d_ws, size_t ws_size,
                              hipStream_t stream) {
  const float* val = (const float*)d_in[0];
  const float* bq  = (const float*)d_in[2];
  const float* bk  = (const float*)d_in[4];
  const float* bv  = (const float*)d_in[6];
  float* out = (float*)d_out;

  u16* valbf = (u16*)d_ws;                              // 8192*1024
  u16* Wbf   = valbf + (size_t)MROWS * EMB;             // 3*1024*1024
  u16* Qb    = Wbf + (size_t)3 * EMB * EMB;
  u16* Kb    = Qb + (size_t)MROWS * EMB;
  u16* VTg   = Kb + (size_t)MROWS * EMB;                // [b*8+h][128 d][4096 s]

  hipLaunchKernelGGL(cvt_f32_bf16, dim3(4096, 4), dim3(256), 0, stream,
                     val, (const float*)d_in[1], (const float*)d_in[3],
                     (const float*)d_in[5], valbf, Wbf);
  hipLaunchKernelGGL(qkv_gemm, dim3(64, 24), dim3(256), 0, stream,
                     valbf, Wbf, bq, bk, bv, Qb, Kb, VTg);
  hipLaunchKernelGGL(local_attn, dim3(16, 32), dim3(256), 0, stream,
                     Qb, Kb, VTg, out);
}

// Round 8
// 187.820 us; speedup vs baseline: 1.0169x; 1.0169x over previous
//
#include <hip/hip_runtime.h>
#include <stdint.h>

#define SEQ   4096
#define EMB   1024
#define HD    128
#define WIN   256
#define MROWS 8192   // SEQ*B

typedef unsigned short u16;
typedef unsigned long long u64;
typedef __bf16 v8bf  __attribute__((ext_vector_type(8)));
typedef float  v4f   __attribute__((ext_vector_type(4)));
typedef u16    v8u16 __attribute__((ext_vector_type(8)));
typedef short  v4ss  __attribute__((ext_vector_type(4)));

// v_mfma_f32_16x16x16_bf16 via inline asm (builtin spelling is unreliable
// across ROCm versions; the ISA instruction is documented for gfx950).
// s_nop 1 guards the VALU-write -> MFMA-read-SrcA/B hazard (the compiler's
// hazard recognizer cannot see through inline asm).
__device__ __forceinline__ void mfma16(v4f& c, v4ss a, v4ss b) {
  asm("s_nop 1\n\tv_mfma_f32_16x16x16_bf16 %0, %1, %2, %0"
      : "+v"(c) : "v"(a), "v"(b));
}

__device__ __forceinline__ u16 f2bf(float f) {
  uint32_t u = __builtin_bit_cast(uint32_t, f);
  u += 0x7FFFu + ((u >> 16) & 1u);
  return (u16)(u >> 16);
}
__device__ __forceinline__ void gl_lds16(const u16* g, u16* l) {
  __builtin_amdgcn_global_load_lds((const __attribute__((address_space(1))) void*)g,
                                   (__attribute__((address_space(3))) void*)l,
                                   16, 0, 0);
}

// ---------------------------------------------------------------------------
// f32 -> bf16 conversion: val (8.4M) and Wq/Wk/Wv (1M each) into workspace.
// ---------------------------------------------------------------------------
__global__ __launch_bounds__(256)
void cvt_f32_bf16(const float* __restrict__ val,
                  const float* __restrict__ Wq,
                  const float* __restrict__ Wk,
                  const float* __restrict__ Wv,
                  u16* __restrict__ valbf, u16* __restrict__ Wbf)
{
  const int seg = blockIdx.y;
  const float* src; u16* dst; int nblk;
  if (seg == 0)      { src = val; dst = valbf;              nblk = 4096; }
  else if (seg == 1) { src = Wq;  dst = Wbf;                nblk = 512;  }
  else if (seg == 2) { src = Wk;  dst = Wbf + (1u << 20);   nblk = 512;  }
  else               { src = Wv;  dst = Wbf + (2u << 20);   nblk = 512;  }
  if ((int)blockIdx.x >= nblk) return;
  const int t = blockIdx.x * 256 + threadIdx.x;   // 8 elems per thread
  float4 a = ((const float4*)src)[2 * t];
  float4 b = ((const float4*)src)[2 * t + 1];
  v8u16 o;
  o[0] = f2bf(a.x); o[1] = f2bf(a.y); o[2] = f2bf(a.z); o[3] = f2bf(a.w);
  o[4] = f2bf(b.x); o[5] = f2bf(b.y); o[6] = f2bf(b.z); o[7] = f2bf(b.w);
  ((v8u16*)dst)[t] = o;
}

// ---------------------------------------------------------------------------
// Fused QKV GEMM (m97 plateau: 39% MfmaUtil, ~920 TF). Q/K row-major
// (attention order); V stored TRANSPOSED as VT[(b*8+h)*128 + d][s].
// ---------------------------------------------------------------------------
__global__ __launch_bounds__(256, 3)
void qkv_gemm(const u16* __restrict__ valbf, const u16* __restrict__ Wbf,
              const float* __restrict__ bq, const float* __restrict__ bk,
              const float* __restrict__ bv,
              u16* __restrict__ Qb, u16* __restrict__ Kb, u16* __restrict__ VTg)
{
  __shared__ __align__(16) u16 As[128 * 64];
  __shared__ __align__(16) u16 Bs[128 * 64];

  const int tid  = threadIdx.x;
  const int lane = tid & 63;
  const int w    = tid >> 6;
  const int quad = lane >> 4;
  const int lq   = lane & 15;
  const int wm   = w >> 1, wn = w & 1;

  const int bm = blockIdx.x;   // 0..63  (fastest -> XCD-local A slab)
  const int bn = blockIdx.y;   // 0..23

  const int seg = bn >> 3;     // 0=Q 1=K 2=V
  const u16*   Wsel = Wbf + (size_t)seg * EMB * EMB;
  const float* bsel = seg == 0 ? bq : (seg == 1 ? bk : bv);
  const int nseg0 = (bn & 7) * 128;

  const u16* arow[4];
  const u16* brow[4];
#pragma unroll
  for (int call = 0; call < 4; ++call) {
    int c  = call * 256 + w * 64 + lane;
    int m  = c >> 3;
    int qs = c & 7;
    int q  = qs ^ (m & 7);
    int a2 = bm * 128 + m;
    int aa = 2 * (a2 & 4095) + (a2 >> 12);
    int grow = (aa & 4095) * 2 + (aa >> 12);
    arow[call] = valbf + (size_t)grow * EMB + q * 8;
    int n = nseg0 + m;
    brow[call] = Wsel + (size_t)n * EMB + q * 8;
  }

  v4f acc[4][4];
#pragma unroll
  for (int mt = 0; mt < 4; ++mt)
#pragma unroll
    for (int nt = 0; nt < 4; ++nt) acc[mt][nt] = (v4f){0.f, 0.f, 0.f, 0.f};

#pragma unroll 1
  for (int kt = 0; kt < 16; ++kt) {
    const int k0 = kt * 64;
    __syncthreads();
#pragma unroll
    for (int call = 0; call < 4; ++call) {
      gl_lds16(arow[call] + k0, &As[(call * 256 + w * 64) * 8]);
      gl_lds16(brow[call] + k0, &Bs[(call * 256 + w * 64) * 8]);
    }
    __syncthreads();
#pragma unroll
    for (int ks = 0; ks < 2; ++ks) {
      v8bf afr[4], bfr[4];
      const int qa = ks * 4 + quad;
#pragma unroll
      for (int mt = 0; mt < 4; ++mt) {
        int m = wm * 64 + mt * 16 + lq;
        afr[mt] = *(const v8bf*)&As[(m * 8 + (qa ^ (m & 7))) * 8];
      }
#pragma unroll
      for (int nt = 0; nt < 4; ++nt) {
        int n = wn * 64 + nt * 16 + lq;
        bfr[nt] = *(const v8bf*)&Bs[(n * 8 + (qa ^ (n & 7))) * 8];
      }
#pragma unroll
      for (int mt = 0; mt < 4; ++mt)
#pragma unroll
        for (int nt = 0; nt < 4; ++nt)
          acc[mt][nt] = __builtin_amdgcn_mfma_f32_16x16x32_bf16(afr[mt], bfr[nt], acc[mt][nt], 0, 0, 0);
    }
  }

  const float scale = 0.08838834764831845f;  // 1/sqrt(128)
  float bias[4];
#pragma unroll
  for (int nt = 0; nt < 4; ++nt)
    bias[nt] = bsel[nseg0 + wn * 64 + nt * 16 + lq];

  if (seg == 2) {
    const int h  = bn & 7;
    const int bp = bm >> 5;
    const int s0 = (bm & 31) * 128;
#pragma unroll
    for (int mt = 0; mt < 4; ++mt) {
      int mb = wm * 64 + mt * 16 + quad * 4;
#pragma unroll
      for (int nt = 0; nt < 4; ++nt) {
        int n = wn * 64 + nt * 16 + lq;   // = d (0..127)
        u64 pk = 0;
#pragma unroll
        for (int r = 0; r < 4; ++r)
          pk |= (u64)f2bf(acc[mt][nt][r] + bias[nt]) << (16 * r);
        *(u64*)&VTg[((size_t)(bp * 8 + h) * HD + n) * SEQ + s0 + mb] = pk;
      }
    }
  } else {
    u16* Osel = (seg == 0) ? Qb : Kb;
#pragma unroll
    for (int mt = 0; mt < 4; ++mt) {
      int rbase = bm * 128 + wm * 64 + mt * 16 + quad * 4;
#pragma unroll
      for (int nt = 0; nt < 4; ++nt) {
        int ncol = nseg0 + wn * 64 + nt * 16 + lq;
#pragma unroll
        for (int r = 0; r < 4; ++r) {
          float v = acc[mt][nt][r] + bias[nt];
          if (seg == 0) v *= scale;
          Osel[(size_t)(rbase + r) * EMB + ncol] = f2bf(v);
        }
      }
    }
  }
}

// ---------------------------------------------------------------------------
// Banded attention, S^T formulation. S^T = K.Q^T (swapped MFMA operands),
// exp in C-layout, then O^T = V^T.P^T via 16x16x16 MFMA whose B operand
// (P^T, k=quad*4+idx) maps IDENTITY onto S^T's C-layout rows (quad*4+r) —
// no LDS P roundtrip. K/V^T single-buffered in 32 KB LDS (-> 4 blocks/CU),
// staged by coalesced global_load_lds, XOR-swizzled. Per-lane denominator
// (query = lq); zero-shift softmax; padding exp(0)=1 in finalize; mask only
// the two extreme band tiles. Output stored as float4.
// ---------------------------------------------------------------------------
__global__ __launch_bounds__(256, 4)
void local_attn(const u16* __restrict__ Qb, const u16* __restrict__ Kb,
                const u16* __restrict__ VTg, float* __restrict__ out)
{
  __shared__ __align__(16) u16 sK [64 * 128];   // K tile  [j][d], swizzled
  __shared__ __align__(16) u16 sVT[128 * 64];   // V^T tile [d][j], swizzled

  const int tid  = threadIdx.x;
  const int lane = tid & 63;
  const int w    = tid >> 6;
  const int quad = lane >> 4;
  const int lq   = lane & 15;

  const int bh = blockIdx.x;        // b'*8 + h
  const int q0 = blockIdx.y * 64;
  const int bp = bh >> 3;
  const int h  = bh & 7;
  const size_t rowbase = (size_t)bp * SEQ;

  const u16* Kbase = Kb + rowbase * EMB + h * HD;       // + j*EMB
  const u16* Vbase = VTg + (size_t)bh * HD * SEQ;       // + d*SEQ

  // Q B-fragments (pre-scaled in GEMM); lane = query q0 + w*16 + lq
  v8bf qf[4];
  {
    const u16* qrow = Qb + (rowbase + q0 + w * 16 + lq) * EMB + h * HD;
#pragma unroll
    for (int ks = 0; ks < 4; ++ks)
      qf[ks] = *(const v8bf*)(qrow + ks * 32 + quad * 8);
  }

  v4f oaccT[8];                      // O^T: col = query (lq), row = d
#pragma unroll
  for (int dt = 0; dt < 8; ++dt) oaccT[dt] = (v4f){0.f, 0.f, 0.f, 0.f};
  float ls = 0.f;                    // per-lane denominator (query = lq)

  const int jlo = (q0 - WIN > 0) ? q0 - WIN : 0;
  const int jhi = (q0 + 64 + WIN < SEQ) ? q0 + 64 + WIN : SEQ;
  const int nit = (jhi - jlo) >> 6;

  auto stage = [&](int kb) {
#pragma unroll
    for (int call = 0; call < 4; ++call) {
      int s = call * 256 + w * 64 + lane;     // K: 16 chunks/row, 64 rows
      int row = s >> 4, sl = s & 15;
      int q = sl ^ (row & 15);
      gl_lds16(Kbase + (size_t)(kb + row) * EMB + q * 8,
               &sK[(call * 256 + w * 64) * 8]);
    }
#pragma unroll
    for (int call = 0; call < 4; ++call) {
      int s = call * 256 + w * 64 + lane;     // VT: 8 chunks/row, 128 rows
      int d = s >> 3, sl = s & 7;
      int q = sl ^ (d & 7);
      gl_lds16(Vbase + (size_t)d * SEQ + kb + q * 8,
               &sVT[(call * 256 + w * 64) * 8]);
    }
  };

#pragma unroll 1
  for (int it = 0; it < nit; ++it) {
    const int kb = jlo + it * 64;
    stage(kb);
    __syncthreads();                 // DMA complete for this tile

    // --- S^T = K Q^T (A = K frag, B = Q frag) ---
    v4f st[4];
#pragma unroll
    for (int nt = 0; nt < 4; ++nt) st[nt] = (v4f){0.f, 0.f, 0.f, 0.f};
#pragma unroll
    for (int ks = 0; ks < 4; ++ks) {
      const int sl = (ks * 4 + quad) ^ lq;
#pragma unroll
      for (int nt = 0; nt < 4; ++nt) {
        v8bf kf = *(const v8bf*)&sK[((nt * 16 + lq) * 16 + sl) * 8];
        st[nt] = __builtin_amdgcn_mfma_f32_16x16x32_bf16(kf, qf[ks], st[nt], 0, 0, 0);
      }
    }

    // --- exp (no shift) + mask (extreme tiles only) + per-lane denom ---
    // st[nt][r] = S[query = q0+w*16+lq][j = kb+nt*16+quad*4+r]
    const bool need_mask = (kb == q0 - 256) || (kb == q0 + 256);
    v4ss pf[4];
#pragma unroll
    for (int nt = 0; nt < 4; ++nt) {
#pragma unroll
      for (int r = 0; r < 4; ++r) {
        float pv = __expf(st[nt][r]);
        if (need_mask) {
          int j  = kb + nt * 16 + quad * 4 + r;
          int sr = q0 + w * 16 + lq;
          int dd = j - sr;
          pv = (dd <= WIN && dd >= -WIN) ? pv : 0.f;
        }
        ls += pv;
        pf[nt][r] = (short)f2bf(pv);
      }
    }

    // --- O^T += V^T P^T (x16 MFMA; P^T maps identity from S^T C-layout) ---
#pragma unroll
    for (int nt = 0; nt < 4; ++nt) {
#pragma unroll
      for (int dt = 0; dt < 8; ++dt) {
        int d = dt * 16 + lq;
        int slot = (nt * 2 + (quad >> 1)) ^ (d & 7);
        v4ss vt = *(const v4ss*)&sVT[(d * 8 + slot) * 8 + (quad & 1) * 4];
        mfma16(oaccT[dt], vt, pf[nt]);
      }
    }
    __syncthreads();                 // all reads done before next overwrite
  }

  // MFMA-write -> VALU-read hazard guard (inline asm is opaque to the
  // compiler's hazard recognizer).
  asm volatile("s_nop 7\n\ts_nop 7");

  // --- finalize: reduce denom over quads, add zero-padding, store float4 ---
  {
    float t = ls;
    t += __shfl_xor(t, 16);
    t += __shfl_xor(t, 32);
    const int sr = q0 + w * 16 + lq;
    int npl = WIN - sr;             if (npl < 0) npl = 0;
    int npr = sr - (SEQ - 1 - WIN); if (npr < 0) npr = 0;
    const float inv = 1.0f / (t + (float)(npl + npr));
    float* orow = out + (size_t)(2 * sr + bp) * EMB + h * HD;
#pragma unroll
    for (int dt = 0; dt < 8; ++dt) {
      v4f o;
#pragma unroll
      for (int r = 0; r < 4; ++r) o[r] = oaccT[dt][r] * inv;
      *(v4f*)(orow + dt * 16 + quad * 4) = o;
    }
  }
}

extern "C" void kernel_launch(void* const* d_in, const int* in_sizes, int n_in,
                              void* d_out, int out_size, void* d_ws, size_t ws_size,
                              hipStream_t stream) {
  const float* val = (const float*)d_in[0];
  const float* bq  = (const float*)d_in[2];
  const float* bk  = (const float*)d_in[4];
  const float* bv  = (const float*)d_in[6];
  float* out = (float*)d_out;

  u16* valbf = (u16*)d_ws;                              // 8192*1024
  u16* Wbf   = valbf + (size_t)MROWS * EMB;             // 3*1024*1024
  u16* Qb    = Wbf + (size_t)3 * EMB * EMB;
  u16* Kb    = Qb + (size_t)MROWS * EMB;
  u16* VTg   = Kb + (size_t)MROWS * EMB;                // [b*8+h][128 d][4096 s]

  hipLaunchKernelGGL(cvt_f32_bf16, dim3(4096, 4), dim3(256), 0, stream,
                     val, (const float*)d_in[1], (const float*)d_in[3],
                     (const float*)d_in[5], valbf, Wbf);
  hipLaunchKernelGGL(qkv_gemm, dim3(64, 24), dim3(256), 0, stream,
                     valbf, Wbf, bq, bk, bv, Qb, Kb, VTg);
  hipLaunchKernelGGL(local_attn, dim3(16, 64), dim3(256), 0, stream,
                     Qb, Kb, VTg, out);
}